// Round 12
// baseline (2102.216 us; speedup 1.0000x reference)
//
#include <hip/hip_runtime.h>
#include <hip/hip_bf16.h>
#include <stdint.h>

#define N_NODES 100000
#define N_REL   16
#define N_EDGE  50000
#define DIM     500
#define TOT_E   (N_REL * N_EDGE)      // 800,000
#define CNT_N   (N_REL * N_NODES)     // 1,600,000

// ws layout (8/16B-aligned):
#define INV_OFF    0ull           // 1.6M u32 cnt -> f32 inv (6,400,000 B)
#define DEG_OFF    6400000ull     // 100k u32
#define ROW_OFF    6800000ull     // 100001 u32
#define SCANP_OFF  7201000ull     // 128 u32
#define CURS_OFF   7210000ull     // 100k u32
#define ELIST_OFF  7610000ull     // 800k uint2 = 6.4MB
#define WB1_OFF    14020000ull    // 512*512 bf16
#define WB2_OFF    14550000ull    // 512*512 bf16
#define H1_OFF     15080000ull    // 50M bf16 (x_bf16 then h1)

typedef __attribute__((ext_vector_type(8))) short bf16x8;
typedef __attribute__((ext_vector_type(4))) float f32x4;

// ---------------- threefry2x32, partitionable-mode mask (R8-verified) ----------------
__device__ __forceinline__ uint32_t rotl32(uint32_t x, int d) {
    return (x << d) | (x >> (32 - d));
}
__device__ __forceinline__ bool edge_keep(uint32_t j) {
    uint32_t x0 = 0u, x1 = j;
    const uint32_t ks0 = 0u, ks1 = 42u, ks2 = 0u ^ 42u ^ 0x1BD11BDAu;
    const int RA[4] = {13, 15, 26, 6};
    const int RB[4] = {17, 29, 16, 24};
    x0 += ks0; x1 += ks1;
#pragma unroll
    for (int i = 0; i < 4; i++) { x0 += x1; x1 = rotl32(x1, RA[i]); x1 ^= x0; }
    x0 += ks1; x1 += ks2 + 1u;
#pragma unroll
    for (int i = 0; i < 4; i++) { x0 += x1; x1 = rotl32(x1, RB[i]); x1 ^= x0; }
    x0 += ks2; x1 += ks0 + 2u;
#pragma unroll
    for (int i = 0; i < 4; i++) { x0 += x1; x1 = rotl32(x1, RA[i]); x1 ^= x0; }
    x0 += ks0; x1 += ks1 + 3u;
#pragma unroll
    for (int i = 0; i < 4; i++) { x0 += x1; x1 = rotl32(x1, RB[i]); x1 ^= x0; }
    x0 += ks1; x1 += ks2 + 4u;
#pragma unroll
    for (int i = 0; i < 4; i++) { x0 += x1; x1 = rotl32(x1, RA[i]); x1 ^= x0; }
    x0 += ks2; x1 += ks0 + 5u;
    return ((x0 ^ x1) >> 31) == 0u;    // XOR fold, MSB==0 <=> keep
}

__device__ __forceinline__ uint16_t f2bf(float f) {
    uint32_t u = __float_as_uint(f);
    u += 0x7FFFu + ((u >> 16) & 1u);
    return (uint16_t)(u >> 16);
}
__device__ __forceinline__ float bf2f(uint16_t v) {
    return __uint_as_float((uint32_t)v << 16);
}

// ---------------- CSR build ----------------
__global__ __launch_bounds__(256) void zero_kernel(uint32_t* __restrict__ p, int n) {
    int t = blockIdx.x * blockDim.x + threadIdx.x;
    if (t < n) p[t] = 0u;
}

__global__ __launch_bounds__(256) void count_kernel(
        const int* __restrict__ eidx, uint32_t* __restrict__ cnt,
        uint32_t* __restrict__ deg) {
    int tid = blockIdx.x * blockDim.x + threadIdx.x;
    if (tid >= TOT_E) return;
    if (edge_keep((uint32_t)tid)) {
        int r = tid / N_EDGE;
        int e = tid - r * N_EDGE;
        int dst = eidx[(r * 2 + 1) * N_EDGE + e];
        atomicAdd(&cnt[r * N_NODES + dst], 1u);
        atomicAdd(&deg[dst], 1u);
    }
}

__global__ __launch_bounds__(256) void inv_kernel(uint32_t* __restrict__ cnt_u,
                                                  float* __restrict__ inv) {
    int t = blockIdx.x * blockDim.x + threadIdx.x;
    if (t < CNT_N) {
        float c = (float)cnt_u[t];
        inv[t] = 1.0f / fmaxf(c, 1.0f);
    }
}

__global__ __launch_bounds__(256) void scan1_kernel(
        const uint32_t* __restrict__ deg, uint32_t* __restrict__ rowptr,
        uint32_t* __restrict__ scanp) {
    __shared__ uint32_t sh[256];
    int b = blockIdx.x, t = threadIdx.x;
    int base = b * 1024 + t * 4;
    uint32_t x[4];
#pragma unroll
    for (int i = 0; i < 4; i++) x[i] = (base + i < N_NODES) ? deg[base + i] : 0u;
    uint32_t s = x[0] + x[1] + x[2] + x[3];
    sh[t] = s; __syncthreads();
    for (int off = 1; off < 256; off <<= 1) {
        uint32_t v = (t >= off) ? sh[t - off] : 0u;
        __syncthreads();
        sh[t] += v;
        __syncthreads();
    }
    uint32_t run = sh[t] - s;
    if (t == 255) scanp[b] = sh[255];
#pragma unroll
    for (int i = 0; i < 4; i++) {
        if (base + i < N_NODES) rowptr[base + i] = run;
        run += x[i];
    }
}

__global__ __launch_bounds__(128) void scan2_kernel(
        uint32_t* __restrict__ scanp, uint32_t* __restrict__ rowptr, int nb) {
    __shared__ uint32_t sh[128];
    int t = threadIdx.x;
    uint32_t v = (t < nb) ? scanp[t] : 0u;
    sh[t] = v; __syncthreads();
    for (int off = 1; off < 128; off <<= 1) {
        uint32_t u = (t >= off) ? sh[t - off] : 0u;
        __syncthreads();
        sh[t] += u;
        __syncthreads();
    }
    if (t < nb) scanp[t] = sh[t] - v;
    if (t == 127) rowptr[N_NODES] = sh[127];
}

__global__ __launch_bounds__(256) void scan3_kernel(
        uint32_t* __restrict__ rowptr, const uint32_t* __restrict__ scanp,
        uint32_t* __restrict__ curs) {
    int b = blockIdx.x, t = threadIdx.x;
    int base = b * 1024 + t * 4;
    uint32_t off = scanp[b];
#pragma unroll
    for (int i = 0; i < 4; i++) {
        int idx = base + i;
        if (idx < N_NODES) {
            uint32_t v = rowptr[idx] + off;
            rowptr[idx] = v;
            curs[idx] = v;
        }
    }
}

// packed per-edge records: {src | r<<20, inv(r,dst)}
__global__ __launch_bounds__(256) void scatter_kernel(
        const int* __restrict__ eidx, const float* __restrict__ inv,
        uint32_t* __restrict__ curs, uint2* __restrict__ elist2) {
    int tid = blockIdx.x * blockDim.x + threadIdx.x;
    if (tid >= TOT_E) return;
    if (edge_keep((uint32_t)tid)) {
        int r = tid / N_EDGE;
        int e = tid - r * N_EDGE;
        int src = eidx[(r * 2 + 0) * N_EDGE + e];
        int dst = eidx[(r * 2 + 1) * N_EDGE + e];
        uint32_t pos = atomicAdd(&curs[dst], 1u);
        uint2 rec;
        rec.x = (uint32_t)src | ((uint32_t)r << 20);
        rec.y = __float_as_uint(inv[r * N_NODES + dst]);
        elist2[pos] = rec;
    }
}

// ---------------- dtype conversion ----------------
__global__ __launch_bounds__(256) void conv_x_kernel(
        const float4* __restrict__ in, ushort4* __restrict__ outp, int n4) {
    int t = blockIdx.x * blockDim.x + threadIdx.x;
    if (t >= n4) return;
    float4 v = in[t];
    ushort4 o;
    o.x = f2bf(v.x); o.y = f2bf(v.y); o.z = f2bf(v.z); o.w = f2bf(v.w);
    outp[t] = o;
}

__global__ __launch_bounds__(256) void conv_w_kernel(
        const float* __restrict__ W, uint16_t* __restrict__ Bt) {
    int idx = blockIdx.x * 256 + threadIdx.x;   // 512*512
    int n = idx >> 9, k = idx & 511;
    float v = (n < DIM && k < DIM) ? W[k * DIM + n] : 0.f;
    Bt[idx] = f2bf(v);
}

// ---------------- MFMA bf16 GEMM (unchanged, passing) ----------------
__global__ __launch_bounds__(256) void gemm_mfma_kernel(
        const uint16_t* __restrict__ A, const uint16_t* __restrict__ Bt,
        float* __restrict__ C, int M) {
    __shared__ uint16_t As[64][72];
    __shared__ uint16_t Bs[64][72];
    int m0 = blockIdx.x * 64;
    int n0 = blockIdx.y * 64;
    int t = threadIdx.x;
    int wave = t >> 6, lane = t & 63;
    int row_s = t >> 2;
    int k4 = (t & 3) * 16;
    f32x4 acc[4] = {};

    for (int k0 = 0; k0 < 512; k0 += 64) {
        {
            int gm = m0 + row_s;
            int gk = k0 + k4;
            uint16_t* dst = &As[row_s][k4];
            if (gm < M && gk + 15 < DIM) {
                *(bf16x8*)dst       = *(const bf16x8*)&A[(long)gm * DIM + gk];
                *(bf16x8*)(dst + 8) = *(const bf16x8*)&A[(long)gm * DIM + gk + 8];
            } else {
#pragma unroll
                for (int i = 0; i < 16; i++)
                    dst[i] = (gm < M && gk + i < DIM) ? A[(long)gm * DIM + gk + i] : (uint16_t)0;
            }
        }
        {
            uint16_t* dst = &Bs[row_s][k4];
            const uint16_t* srcp = &Bt[(n0 + row_s) * 512 + k0 + k4];
            *(bf16x8*)dst       = *(const bf16x8*)srcp;
            *(bf16x8*)(dst + 8) = *(const bf16x8*)(srcp + 8);
        }
        __syncthreads();

        int rA = (wave << 4) + (lane & 15);
        int ks = (lane >> 4) * 8;
        bf16x8 a0 = *(const bf16x8*)&As[rA][ks];
        bf16x8 a1 = *(const bf16x8*)&As[rA][32 + ks];
#pragma unroll
        for (int nt = 0; nt < 4; nt++) {
            int cB = (nt << 4) + (lane & 15);
            bf16x8 b0 = *(const bf16x8*)&Bs[cB][ks];
            bf16x8 b1 = *(const bf16x8*)&Bs[cB][32 + ks];
            acc[nt] = __builtin_amdgcn_mfma_f32_16x16x32_bf16(a0, b0, acc[nt], 0, 0, 0);
            acc[nt] = __builtin_amdgcn_mfma_f32_16x16x32_bf16(a1, b1, acc[nt], 0, 0, 0);
        }
        __syncthreads();
    }

    int rbase = m0 + (wave << 4) + ((lane >> 4) << 2);
    int cl = lane & 15;
#pragma unroll
    for (int nt = 0; nt < 4; nt++) {
        int col = n0 + (nt << 4) + cl;
        if (col < DIM) {
#pragma unroll
            for (int q = 0; q < 4; q++) {
                int rr = rbase + q;
                if (rr < M) C[(long)rr * DIM + col] = acc[nt][q];
            }
        }
    }
}

// ---------------- direct-load gather, 2-edge unroll, no LDS ----------------
// Wave wv of block n owns dims [125*wv, 125*wv+125). Lane l computes dims
// j0=l and j1=l+64 (if <125). Per edge each lane loads its 5 h-inputs and 5
// weights straight to registers (5-lane groups share addresses -> L1
// broadcast). Two edges per iteration -> all 4 dot-products' loads in flight
// together; only loop-carried dep is the accumulator FMA.
template <bool BF16H, bool OUT_BF16>
__global__ __launch_bounds__(256) void gather_kernel(
        const void* __restrict__ h, const float* __restrict__ w_rel,
        const uint2* __restrict__ elist2, const uint32_t* __restrict__ rowptr,
        const float* __restrict__ self_in, float* __restrict__ out_f32,
        uint16_t* __restrict__ out_bf16) {
    int n = blockIdx.x;
    int wv = threadIdx.x >> 6, l = threadIdx.x & 63;
    const int D0 = wv * 125;
    const int j0 = l, j1 = l + 64;
    const bool has1 = (j1 < 125);
    const int b0 = j0 / 5, c0 = j0 - b0 * 5;
    const int b1 = j1 / 5, c1 = j1 - b1 * 5;
    // per-lane weight offsets within a relation's chunk slab (625 floats)
    const int wo0 = b0 * 25 + c0;            // + i*5 walks the 5 inputs
    const int wo1 = b1 * 25 + c1;
    const long ho0 = (long)D0 + b0 * 5;      // h slice offset for j0
    const long ho1 = (long)D0 + b1 * 5;

    uint32_t s = rowptr[n], e = rowptr[n + 1];
    float a0 = 0.f, a1 = 0.f;

#define LOADH5(dst, src, hoff)                                            \
    do {                                                                  \
        if constexpr (BF16H) {                                            \
            const uint16_t* hp_ = (const uint16_t*)h + (long)(src) * DIM + (hoff); \
            _Pragma("unroll")                                             \
            for (int i_ = 0; i_ < 5; i_++) dst[i_] = bf2f(hp_[i_]);       \
        } else {                                                          \
            const float* hp_ = (const float*)h + (long)(src) * DIM + (hoff); \
            _Pragma("unroll")                                             \
            for (int i_ = 0; i_ < 5; i_++) dst[i_] = hp_[i_];             \
        }                                                                 \
    } while (0)

#define LOADW5(dst, wbase, woff)                                          \
    do {                                                                  \
        _Pragma("unroll")                                                 \
        for (int i_ = 0; i_ < 5; i_++) dst[i_] = (wbase)[(woff) + i_ * 5]; \
    } while (0)

    uint32_t p = s;
    for (; p + 2 <= e; p += 2) {
        uint2 rA = elist2[p];
        uint2 rB = elist2[p + 1];
        uint32_t srcA = rA.x & 0xFFFFFu, rlA = rA.x >> 20;
        uint32_t srcB = rB.x & 0xFFFFFu, rlB = rB.x >> 20;
        float iA = __uint_as_float(rA.y);
        float iB = __uint_as_float(rB.y);
        const float* wbA = w_rel + (size_t)rlA * 2500 + (size_t)wv * 625;
        const float* wbB = w_rel + (size_t)rlB * 2500 + (size_t)wv * 625;

        float hA0[5], hB0[5], wA0[5], wB0[5];
        LOADH5(hA0, srcA, ho0);
        LOADH5(hB0, srcB, ho0);
        LOADW5(wA0, wbA, wo0);
        LOADW5(wB0, wbB, wo0);
        float hA1[5], hB1[5], wA1[5], wB1[5];
        if (has1) {
            LOADH5(hA1, srcA, ho1);
            LOADH5(hB1, srcB, ho1);
            LOADW5(wA1, wbA, wo1);
            LOADW5(wB1, wbB, wo1);
        }

        float dA0 = hA0[0]*wA0[0] + hA0[1]*wA0[1] + hA0[2]*wA0[2] + hA0[3]*wA0[3] + hA0[4]*wA0[4];
        float dB0 = hB0[0]*wB0[0] + hB0[1]*wB0[1] + hB0[2]*wB0[2] + hB0[3]*wB0[3] + hB0[4]*wB0[4];
        a0 = fmaf(iA, dA0, a0);
        a0 = fmaf(iB, dB0, a0);
        if (has1) {
            float dA1 = hA1[0]*wA1[0] + hA1[1]*wA1[1] + hA1[2]*wA1[2] + hA1[3]*wA1[3] + hA1[4]*wA1[4];
            float dB1 = hB1[0]*wB1[0] + hB1[1]*wB1[1] + hB1[2]*wB1[2] + hB1[3]*wB1[3] + hB1[4]*wB1[4];
            a1 = fmaf(iA, dA1, a1);
            a1 = fmaf(iB, dB1, a1);
        }
    }
    if (p < e) {   // odd tail
        uint2 rA = elist2[p];
        uint32_t srcA = rA.x & 0xFFFFFu, rlA = rA.x >> 20;
        float iA = __uint_as_float(rA.y);
        const float* wbA = w_rel + (size_t)rlA * 2500 + (size_t)wv * 625;
        float hA0[5], wA0[5];
        LOADH5(hA0, srcA, ho0);
        LOADW5(wA0, wbA, wo0);
        float dA0 = hA0[0]*wA0[0] + hA0[1]*wA0[1] + hA0[2]*wA0[2] + hA0[3]*wA0[3] + hA0[4]*wA0[4];
        a0 = fmaf(iA, dA0, a0);
        if (has1) {
            float hA1[5], wA1[5];
            LOADH5(hA1, srcA, ho1);
            LOADW5(wA1, wbA, wo1);
            float dA1 = hA1[0]*wA1[0] + hA1[1]*wA1[1] + hA1[2]*wA1[2] + hA1[3]*wA1[3] + hA1[4]*wA1[4];
            a1 = fmaf(iA, dA1, a1);
        }
    }
#undef LOADH5
#undef LOADW5

    long ob = (long)n * DIM + D0;
    {
        float v = fmaxf(self_in[ob + j0] + a0, 0.f);
        if (OUT_BF16) out_bf16[ob + j0] = f2bf(v);
        else          out_f32[ob + j0] = v;
    }
    if (has1) {
        float v = fmaxf(self_in[ob + j1] + a1, 0.f);
        if (OUT_BF16) out_bf16[ob + j1] = f2bf(v);
        else          out_f32[ob + j1] = v;
    }
}

extern "C" void kernel_launch(void* const* d_in, const int* in_sizes, int n_in,
                              void* d_out, int out_size, void* d_ws, size_t ws_size,
                              hipStream_t stream) {
    const float* x       = nullptr;
    const float* w_rel1  = nullptr;
    const float* w_rel2  = nullptr;
    const float* w_self1 = nullptr;
    const float* w_self2 = nullptr;
    const int*   eidx    = nullptr;
    for (int i = 0; i < n_in; i++) {
        int s = in_sizes[i];
        if (s == N_NODES * DIM) {
            x = (const float*)d_in[i];
        } else if (s == N_REL * 100 * 25) {
            if (!w_rel1) w_rel1 = (const float*)d_in[i];
            else         w_rel2 = (const float*)d_in[i];
        } else if (s == DIM * DIM) {
            if (!w_self1) w_self1 = (const float*)d_in[i];
            else          w_self2 = (const float*)d_in[i];
        } else if (s == N_REL * 2 * N_EDGE) {
            eidx = (const int*)d_in[i];
        }
    }
    float* out = (float*)d_out;

    char* ws = (char*)d_ws;
    uint32_t* cnt_u  = (uint32_t*)(ws + INV_OFF);
    float*    inv    = (float*)(ws + INV_OFF);
    uint32_t* deg    = (uint32_t*)(ws + DEG_OFF);
    uint32_t* rowptr = (uint32_t*)(ws + ROW_OFF);
    uint32_t* scanp  = (uint32_t*)(ws + SCANP_OFF);
    uint32_t* curs   = (uint32_t*)(ws + CURS_OFF);
    uint2*    elist2 = (uint2*)(ws + ELIST_OFF);
    uint16_t* wb1    = (uint16_t*)(ws + WB1_OFF);
    uint16_t* wb2    = (uint16_t*)(ws + WB2_OFF);
    uint16_t* h1     = (uint16_t*)(ws + H1_OFF);

    const int NB = (N_NODES + 1023) / 1024;

    // CSR build
    zero_kernel<<<(CNT_N + N_NODES + 255) / 256, 256, 0, stream>>>(cnt_u, CNT_N + N_NODES);
    count_kernel<<<(TOT_E + 255) / 256, 256, 0, stream>>>(eidx, cnt_u, deg);
    inv_kernel<<<(CNT_N + 255) / 256, 256, 0, stream>>>(cnt_u, inv);
    scan1_kernel<<<NB, 256, 0, stream>>>(deg, rowptr, scanp);
    scan2_kernel<<<1, 128, 0, stream>>>(scanp, rowptr, NB);
    scan3_kernel<<<NB, 256, 0, stream>>>(rowptr, scanp, curs);
    scatter_kernel<<<(TOT_E + 255) / 256, 256, 0, stream>>>(eidx, inv, curs, elist2);

    // bf16 conversions
    conv_x_kernel<<<(N_NODES * DIM / 4 + 255) / 256, 256, 0, stream>>>(
        (const float4*)x, (ushort4*)h1, N_NODES * DIM / 4);
    conv_w_kernel<<<512 * 512 / 256, 256, 0, stream>>>(w_self1, wb1);
    conv_w_kernel<<<512 * 512 / 256, 256, 0, stream>>>(w_self2, wb2);

    dim3 ggrid((N_NODES + 63) / 64, 8);

    // layer 1: out(f32) = x_bf16 @ w_self1 (MFMA); h1 = relu(out + msgs(x_f32)) [bf16]
    gemm_mfma_kernel<<<ggrid, 256, 0, stream>>>(h1, wb1, out, N_NODES);
    gather_kernel<false, true><<<N_NODES, 256, 0, stream>>>(
        x, w_rel1, elist2, rowptr, out, nullptr, h1);

    // layer 2: out(f32) = h1 @ w_self2 (MFMA); out = relu(out + msgs(h1))
    gemm_mfma_kernel<<<ggrid, 256, 0, stream>>>(h1, wb2, out, N_NODES);
    gather_kernel<true, false><<<N_NODES, 256, 0, stream>>>(
        h1, w_rel2, elist2, rowptr, out, out, nullptr);
}

// Round 13
// 1754.159 us; speedup vs baseline: 1.1984x; 1.1984x over previous
//
#include <hip/hip_runtime.h>
#include <hip/hip_bf16.h>
#include <stdint.h>

#define N_NODES 100000
#define N_REL   16
#define N_EDGE  50000
#define DIM     500
#define TOT_E   (N_REL * N_EDGE)      // 800,000
#define CNT_N   (N_REL * N_NODES)     // 1,600,000

// ws layout (8/16B-aligned):
#define INV_OFF    0ull           // 1.6M u32 cnt -> f32 inv (6,400,000 B)
#define DEG_OFF    6400000ull     // 100k u32
#define ROW_OFF    6800000ull     // 100001 u32
#define SCANP_OFF  7201000ull     // 128 u32
#define CURS_OFF   7210000ull     // 100k u32
#define ELIST_OFF  7610000ull     // 800k uint2 = 6.4MB
#define WB1_OFF    14020000ull    // 512*512 bf16
#define WB2_OFF    14550000ull    // 512*512 bf16
#define H1_OFF     15080000ull    // 50M bf16 (x_bf16 then h1)

typedef __attribute__((ext_vector_type(8))) short bf16x8;
typedef __attribute__((ext_vector_type(4))) float f32x4;

// ---------------- threefry2x32, partitionable-mode mask (R8-verified) ----------------
__device__ __forceinline__ uint32_t rotl32(uint32_t x, int d) {
    return (x << d) | (x >> (32 - d));
}
__device__ __forceinline__ bool edge_keep(uint32_t j) {
    uint32_t x0 = 0u, x1 = j;
    const uint32_t ks0 = 0u, ks1 = 42u, ks2 = 0u ^ 42u ^ 0x1BD11BDAu;
    const int RA[4] = {13, 15, 26, 6};
    const int RB[4] = {17, 29, 16, 24};
    x0 += ks0; x1 += ks1;
#pragma unroll
    for (int i = 0; i < 4; i++) { x0 += x1; x1 = rotl32(x1, RA[i]); x1 ^= x0; }
    x0 += ks1; x1 += ks2 + 1u;
#pragma unroll
    for (int i = 0; i < 4; i++) { x0 += x1; x1 = rotl32(x1, RB[i]); x1 ^= x0; }
    x0 += ks2; x1 += ks0 + 2u;
#pragma unroll
    for (int i = 0; i < 4; i++) { x0 += x1; x1 = rotl32(x1, RA[i]); x1 ^= x0; }
    x0 += ks0; x1 += ks1 + 3u;
#pragma unroll
    for (int i = 0; i < 4; i++) { x0 += x1; x1 = rotl32(x1, RB[i]); x1 ^= x0; }
    x0 += ks1; x1 += ks2 + 4u;
#pragma unroll
    for (int i = 0; i < 4; i++) { x0 += x1; x1 = rotl32(x1, RA[i]); x1 ^= x0; }
    x0 += ks2; x1 += ks0 + 5u;
    return ((x0 ^ x1) >> 31) == 0u;    // XOR fold, MSB==0 <=> keep
}

__device__ __forceinline__ uint16_t f2bf(float f) {
    uint32_t u = __float_as_uint(f);
    u += 0x7FFFu + ((u >> 16) & 1u);
    return (uint16_t)(u >> 16);
}
__device__ __forceinline__ float bf2f(uint16_t v) {
    return __uint_as_float((uint32_t)v << 16);
}

// ---------------- CSR build ----------------
__global__ __launch_bounds__(256) void zero_kernel(uint32_t* __restrict__ p, int n) {
    int t = blockIdx.x * blockDim.x + threadIdx.x;
    if (t < n) p[t] = 0u;
}

__global__ __launch_bounds__(256) void count_kernel(
        const int* __restrict__ eidx, uint32_t* __restrict__ cnt,
        uint32_t* __restrict__ deg) {
    int tid = blockIdx.x * blockDim.x + threadIdx.x;
    if (tid >= TOT_E) return;
    if (edge_keep((uint32_t)tid)) {
        int r = tid / N_EDGE;
        int e = tid - r * N_EDGE;
        int dst = eidx[(r * 2 + 1) * N_EDGE + e];
        atomicAdd(&cnt[r * N_NODES + dst], 1u);
        atomicAdd(&deg[dst], 1u);
    }
}

__global__ __launch_bounds__(256) void inv_kernel(uint32_t* __restrict__ cnt_u,
                                                  float* __restrict__ inv) {
    int t = blockIdx.x * blockDim.x + threadIdx.x;
    if (t < CNT_N) {
        float c = (float)cnt_u[t];
        inv[t] = 1.0f / fmaxf(c, 1.0f);
    }
}

__global__ __launch_bounds__(256) void scan1_kernel(
        const uint32_t* __restrict__ deg, uint32_t* __restrict__ rowptr,
        uint32_t* __restrict__ scanp) {
    __shared__ uint32_t sh[256];
    int b = blockIdx.x, t = threadIdx.x;
    int base = b * 1024 + t * 4;
    uint32_t x[4];
#pragma unroll
    for (int i = 0; i < 4; i++) x[i] = (base + i < N_NODES) ? deg[base + i] : 0u;
    uint32_t s = x[0] + x[1] + x[2] + x[3];
    sh[t] = s; __syncthreads();
    for (int off = 1; off < 256; off <<= 1) {
        uint32_t v = (t >= off) ? sh[t - off] : 0u;
        __syncthreads();
        sh[t] += v;
        __syncthreads();
    }
    uint32_t run = sh[t] - s;
    if (t == 255) scanp[b] = sh[255];
#pragma unroll
    for (int i = 0; i < 4; i++) {
        if (base + i < N_NODES) rowptr[base + i] = run;
        run += x[i];
    }
}

__global__ __launch_bounds__(128) void scan2_kernel(
        uint32_t* __restrict__ scanp, uint32_t* __restrict__ rowptr, int nb) {
    __shared__ uint32_t sh[128];
    int t = threadIdx.x;
    uint32_t v = (t < nb) ? scanp[t] : 0u;
    sh[t] = v; __syncthreads();
    for (int off = 1; off < 128; off <<= 1) {
        uint32_t u = (t >= off) ? sh[t - off] : 0u;
        __syncthreads();
        sh[t] += u;
        __syncthreads();
    }
    if (t < nb) scanp[t] = sh[t] - v;
    if (t == 127) rowptr[N_NODES] = sh[127];
}

__global__ __launch_bounds__(256) void scan3_kernel(
        uint32_t* __restrict__ rowptr, const uint32_t* __restrict__ scanp,
        uint32_t* __restrict__ curs) {
    int b = blockIdx.x, t = threadIdx.x;
    int base = b * 1024 + t * 4;
    uint32_t off = scanp[b];
#pragma unroll
    for (int i = 0; i < 4; i++) {
        int idx = base + i;
        if (idx < N_NODES) {
            uint32_t v = rowptr[idx] + off;
            rowptr[idx] = v;
            curs[idx] = v;
        }
    }
}

// packed per-edge records: {src | r<<20, inv(r,dst)}
__global__ __launch_bounds__(256) void scatter_kernel(
        const int* __restrict__ eidx, const float* __restrict__ inv,
        uint32_t* __restrict__ curs, uint2* __restrict__ elist2) {
    int tid = blockIdx.x * blockDim.x + threadIdx.x;
    if (tid >= TOT_E) return;
    if (edge_keep((uint32_t)tid)) {
        int r = tid / N_EDGE;
        int e = tid - r * N_EDGE;
        int src = eidx[(r * 2 + 0) * N_EDGE + e];
        int dst = eidx[(r * 2 + 1) * N_EDGE + e];
        uint32_t pos = atomicAdd(&curs[dst], 1u);
        uint2 rec;
        rec.x = (uint32_t)src | ((uint32_t)r << 20);
        rec.y = __float_as_uint(inv[r * N_NODES + dst]);
        elist2[pos] = rec;
    }
}

// ---------------- dtype conversion ----------------
__global__ __launch_bounds__(256) void conv_x_kernel(
        const float4* __restrict__ in, ushort4* __restrict__ outp, int n4) {
    int t = blockIdx.x * blockDim.x + threadIdx.x;
    if (t >= n4) return;
    float4 v = in[t];
    ushort4 o;
    o.x = f2bf(v.x); o.y = f2bf(v.y); o.z = f2bf(v.z); o.w = f2bf(v.w);
    outp[t] = o;
}

__global__ __launch_bounds__(256) void conv_w_kernel(
        const float* __restrict__ W, uint16_t* __restrict__ Bt) {
    int idx = blockIdx.x * 256 + threadIdx.x;   // 512*512
    int n = idx >> 9, k = idx & 511;
    float v = (n < DIM && k < DIM) ? W[k * DIM + n] : 0.f;
    Bt[idx] = f2bf(v);
}

// ---------------- MFMA bf16 GEMM (unchanged, passing) ----------------
__global__ __launch_bounds__(256) void gemm_mfma_kernel(
        const uint16_t* __restrict__ A, const uint16_t* __restrict__ Bt,
        float* __restrict__ C, int M) {
    __shared__ uint16_t As[64][72];
    __shared__ uint16_t Bs[64][72];
    int m0 = blockIdx.x * 64;
    int n0 = blockIdx.y * 64;
    int t = threadIdx.x;
    int wave = t >> 6, lane = t & 63;
    int row_s = t >> 2;
    int k4 = (t & 3) * 16;
    f32x4 acc[4] = {};

    for (int k0 = 0; k0 < 512; k0 += 64) {
        {
            int gm = m0 + row_s;
            int gk = k0 + k4;
            uint16_t* dst = &As[row_s][k4];
            if (gm < M && gk + 15 < DIM) {
                *(bf16x8*)dst       = *(const bf16x8*)&A[(long)gm * DIM + gk];
                *(bf16x8*)(dst + 8) = *(const bf16x8*)&A[(long)gm * DIM + gk + 8];
            } else {
#pragma unroll
                for (int i = 0; i < 16; i++)
                    dst[i] = (gm < M && gk + i < DIM) ? A[(long)gm * DIM + gk + i] : (uint16_t)0;
            }
        }
        {
            uint16_t* dst = &Bs[row_s][k4];
            const uint16_t* srcp = &Bt[(n0 + row_s) * 512 + k0 + k4];
            *(bf16x8*)dst       = *(const bf16x8*)srcp;
            *(bf16x8*)(dst + 8) = *(const bf16x8*)(srcp + 8);
        }
        __syncthreads();

        int rA = (wave << 4) + (lane & 15);
        int ks = (lane >> 4) * 8;
        bf16x8 a0 = *(const bf16x8*)&As[rA][ks];
        bf16x8 a1 = *(const bf16x8*)&As[rA][32 + ks];
#pragma unroll
        for (int nt = 0; nt < 4; nt++) {
            int cB = (nt << 4) + (lane & 15);
            bf16x8 b0 = *(const bf16x8*)&Bs[cB][ks];
            bf16x8 b1 = *(const bf16x8*)&Bs[cB][32 + ks];
            acc[nt] = __builtin_amdgcn_mfma_f32_16x16x32_bf16(a0, b0, acc[nt], 0, 0, 0);
            acc[nt] = __builtin_amdgcn_mfma_f32_16x16x32_bf16(a1, b1, acc[nt], 0, 0, 0);
        }
        __syncthreads();
    }

    int rbase = m0 + (wave << 4) + ((lane >> 4) << 2);
    int cl = lane & 15;
#pragma unroll
    for (int nt = 0; nt < 4; nt++) {
        int col = n0 + (nt << 4) + cl;
        if (col < DIM) {
#pragma unroll
            for (int q = 0; q < 4; q++) {
                int rr = rbase + q;
                if (rr < M) C[(long)rr * DIM + col] = acc[nt][q];
            }
        }
    }
}

// ---------------- batched-latency gather (R11 shape + 4-edge stage pipeline) ----------------
// Wave wv of block n owns dims [125*wv, 125*wv+125). Edges processed in
// batches of 4: stage 1 issues all rec loads, stage 2 issues all row-slice
// loads (coalesced, into registers), stage 3 does per-edge LDS distribution
// + dot + fma (w loads hoistable across the unrolled batch). All batch
// predicates are wave-uniform. No barriers (wave-local LDS, in-order DS).
template <bool BF16H, bool OUT_BF16>
__global__ __launch_bounds__(256) void gather_kernel(
        const void* __restrict__ h, const float* __restrict__ w_rel,
        const uint2* __restrict__ elist2, const uint32_t* __restrict__ rowptr,
        const float* __restrict__ self_in, float* __restrict__ out_f32,
        uint16_t* __restrict__ out_bf16) {
    int n = blockIdx.x;
    int wv = threadIdx.x >> 6, l = threadIdx.x & 63;
    const int D0 = wv * 125;
    const int j0 = l, j1 = l + 64;
    const bool has1 = (j1 < 125);
    const int b0 = j0 / 5, c0 = j0 - b0 * 5;
    const int b1 = j1 / 5, c1 = j1 - b1 * 5;
    const int wo0 = b0 * 25 + c0;      // + q*5 walks the 5 inputs
    const int wo1 = b1 * 25 + c1;

    __shared__ float hsb[4][2][128];   // [wave][buf][dim]

    uint32_t s = rowptr[n], e = rowptr[n + 1];
    float a0 = 0.f, a1 = 0.f;

    for (uint32_t p = s; p < e; p += 4) {
        const int k = (int)min(4u, e - p);

        // ---- stage 1: all rec loads issue together ----
        uint2 rec[4];
#pragma unroll
        for (int i = 0; i < 4; i++) {
            if (i < k) rec[i] = elist2[p + i];
        }

        // ---- stage 2: all row-slice loads issue together (registers) ----
        float v0[4], v1[4];
#pragma unroll
        for (int i = 0; i < 4; i++) {
            if (i < k) {
                uint32_t src = rec[i].x & 0xFFFFFu;
                if constexpr (BF16H) {
                    const uint16_t* row = (const uint16_t*)h + (size_t)src * DIM + D0;
                    v0[i] = bf2f(row[j0]);
                    v1[i] = has1 ? bf2f(row[j1]) : 0.f;
                } else {
                    const float* row = (const float*)h + (size_t)src * DIM + D0;
                    v0[i] = row[j0];
                    v1[i] = has1 ? row[j1] : 0.f;
                }
            }
        }

        // ---- stage 3: per-edge LDS distribute + dot + fma ----
#pragma unroll
        for (int i = 0; i < 4; i++) {
            if (i < k) {
                float* hs = hsb[wv][i & 1];
                hs[j0] = v0[i];
                if (has1) hs[j1] = v1[i];
                uint32_t rl = rec[i].x >> 20;
                float inv = __uint_as_float(rec[i].y);
                const float* wb = w_rel + (size_t)rl * 2500 + (size_t)wv * 625;
                float w0[5];
#pragma unroll
                for (int q = 0; q < 5; q++) w0[q] = wb[wo0 + q * 5];
                const float* hp0 = hs + b0 * 5;
                float d0 = hp0[0] * w0[0] + hp0[1] * w0[1] + hp0[2] * w0[2]
                         + hp0[3] * w0[3] + hp0[4] * w0[4];
                a0 = fmaf(inv, d0, a0);
                if (has1) {
                    float w1[5];
#pragma unroll
                    for (int q = 0; q < 5; q++) w1[q] = wb[wo1 + q * 5];
                    const float* hp1 = hs + b1 * 5;
                    float d1 = hp1[0] * w1[0] + hp1[1] * w1[1] + hp1[2] * w1[2]
                             + hp1[3] * w1[3] + hp1[4] * w1[4];
                    a1 = fmaf(inv, d1, a1);
                }
            }
        }
    }

    long ob = (long)n * DIM + D0;
    {
        float v = fmaxf(self_in[ob + j0] + a0, 0.f);
        if (OUT_BF16) out_bf16[ob + j0] = f2bf(v);
        else          out_f32[ob + j0] = v;
    }
    if (has1) {
        float v = fmaxf(self_in[ob + j1] + a1, 0.f);
        if (OUT_BF16) out_bf16[ob + j1] = f2bf(v);
        else          out_f32[ob + j1] = v;
    }
}

extern "C" void kernel_launch(void* const* d_in, const int* in_sizes, int n_in,
                              void* d_out, int out_size, void* d_ws, size_t ws_size,
                              hipStream_t stream) {
    const float* x       = nullptr;
    const float* w_rel1  = nullptr;
    const float* w_rel2  = nullptr;
    const float* w_self1 = nullptr;
    const float* w_self2 = nullptr;
    const int*   eidx    = nullptr;
    for (int i = 0; i < n_in; i++) {
        int s = in_sizes[i];
        if (s == N_NODES * DIM) {
            x = (const float*)d_in[i];
        } else if (s == N_REL * 100 * 25) {
            if (!w_rel1) w_rel1 = (const float*)d_in[i];
            else         w_rel2 = (const float*)d_in[i];
        } else if (s == DIM * DIM) {
            if (!w_self1) w_self1 = (const float*)d_in[i];
            else          w_self2 = (const float*)d_in[i];
        } else if (s == N_REL * 2 * N_EDGE) {
            eidx = (const int*)d_in[i];
        }
    }
    float* out = (float*)d_out;

    char* ws = (char*)d_ws;
    uint32_t* cnt_u  = (uint32_t*)(ws + INV_OFF);
    float*    inv    = (float*)(ws + INV_OFF);
    uint32_t* deg    = (uint32_t*)(ws + DEG_OFF);
    uint32_t* rowptr = (uint32_t*)(ws + ROW_OFF);
    uint32_t* scanp  = (uint32_t*)(ws + SCANP_OFF);
    uint32_t* curs   = (uint32_t*)(ws + CURS_OFF);
    uint2*    elist2 = (uint2*)(ws + ELIST_OFF);
    uint16_t* wb1    = (uint16_t*)(ws + WB1_OFF);
    uint16_t* wb2    = (uint16_t*)(ws + WB2_OFF);
    uint16_t* h1     = (uint16_t*)(ws + H1_OFF);

    const int NB = (N_NODES + 1023) / 1024;

    // CSR build
    zero_kernel<<<(CNT_N + N_NODES + 255) / 256, 256, 0, stream>>>(cnt_u, CNT_N + N_NODES);
    count_kernel<<<(TOT_E + 255) / 256, 256, 0, stream>>>(eidx, cnt_u, deg);
    inv_kernel<<<(CNT_N + 255) / 256, 256, 0, stream>>>(cnt_u, inv);
    scan1_kernel<<<NB, 256, 0, stream>>>(deg, rowptr, scanp);
    scan2_kernel<<<1, 128, 0, stream>>>(scanp, rowptr, NB);
    scan3_kernel<<<NB, 256, 0, stream>>>(rowptr, scanp, curs);
    scatter_kernel<<<(TOT_E + 255) / 256, 256, 0, stream>>>(eidx, inv, curs, elist2);

    // bf16 conversions
    conv_x_kernel<<<(N_NODES * DIM / 4 + 255) / 256, 256, 0, stream>>>(
        (const float4*)x, (ushort4*)h1, N_NODES * DIM / 4);
    conv_w_kernel<<<512 * 512 / 256, 256, 0, stream>>>(w_self1, wb1);
    conv_w_kernel<<<512 * 512 / 256, 256, 0, stream>>>(w_self2, wb2);

    dim3 ggrid((N_NODES + 63) / 64, 8);

    // layer 1: out(f32) = x_bf16 @ w_self1 (MFMA); h1 = relu(out + msgs(x_f32)) [bf16]
    gemm_mfma_kernel<<<ggrid, 256, 0, stream>>>(h1, wb1, out, N_NODES);
    gather_kernel<false, true><<<N_NODES, 256, 0, stream>>>(
        x, w_rel1, elist2, rowptr, out, nullptr, h1);

    // layer 2: out(f32) = h1 @ w_self2 (MFMA); out = relu(out + msgs(h1))
    gemm_mfma_kernel<<<ggrid, 256, 0, stream>>>(h1, wb2, out, N_NODES);
    gather_kernel<true, false><<<N_NODES, 256, 0, stream>>>(
        h1, w_rel2, elist2, rowptr, out, out, nullptr);
}